// Round 9
// baseline (263.966 us; speedup 1.0000x reference)
//
#include <hip/hip_runtime.h>
#include <hip/hip_bf16.h>

typedef __bf16 bf16_t;
typedef __bf16 bf16x4 __attribute__((ext_vector_type(4)));
typedef __bf16 bf16x8 __attribute__((ext_vector_type(8)));
typedef float  f32x4  __attribute__((ext_vector_type(4)));

// ---------------------------------------------------------------- helpers
__device__ __forceinline__ void gload_lds16(const void* g, void* l)
{
    __builtin_amdgcn_global_load_lds((__attribute__((address_space(1))) void*)g,
                                     (__attribute__((address_space(3))) void*)l,
                                     16, 0, 0);
}

// ---------------------------------------------------------------- fused fp32 -> bf16 casts (x1|x2 -> xcat, W1, W2)
__global__ __launch_bounds__(256) void cast_all(const float* __restrict__ x1, const float* __restrict__ x2,
                                                const float* __restrict__ W1, const float* __restrict__ W2,
                                                bf16_t* __restrict__ xcatb, bf16_t* __restrict__ W1b,
                                                bf16_t* __restrict__ W2b)
{
    const size_t i  = ((size_t)blockIdx.x * 256 + threadIdx.x) * 4;
    const size_t M4 = 1ull << 22;              // 4M elements per region
    const size_t r  = i >> 22;
    const size_t off = i & (M4 - 1);
    const float* src; bf16_t* dst;
    if (r == 0)      { src = x1; dst = xcatb; }
    else if (r == 1) { src = x2; dst = xcatb + M4; }
    else if (r == 2) { src = W1; dst = W1b; }
    else             { src = W2; dst = W2b; }
    f32x4 v = *(const f32x4*)(src + off);
    bf16x4 o;
    o[0] = (bf16_t)v[0]; o[1] = (bf16_t)v[1]; o[2] = (bf16_t)v[2]; o[3] = (bf16_t)v[3];
    *(bf16x4*)(dst + off) = o;
}

// ---------------------------------------------------------------- 8-phase-class 256x256 GEMM (GEMM1 only, mode-1 epilogue)
// BM=BN=256, BK=64 split in k32 units; ring of 4 units per matrix (128 KB LDS, dbuf-2-tiles);
// 8 waves (2m x 4n), per-wave 128x64, acc[8][4]; per K-tile 4 phases, each {ds_read, stage, [vmcnt(4)],
// barrier, setprio+16 MFMA+setprio, barrier}. Counted vmcnt: never 0 in the main loop.
// LDS swizzle: element (row,kchunk c) stored at c^(row&3); inverse applied on the global staging source.
__global__ __launch_bounds__(512, 2) void gemm8(
    const bf16_t* __restrict__ A, const bf16_t* __restrict__ B,
    const float* __restrict__ bias, bf16_t* __restrict__ C,
    float* __restrict__ ps, float* __restrict__ ps2)
{
    __shared__ bf16_t lsA[4][256 * 32];
    __shared__ bf16_t lsB[4][256 * 32];
    __shared__ float  cs2[8][64], cq2[8][64];
    const int tid  = threadIdx.x;
    const int lane = tid & 63;
    const int wave = tid >> 6;
    const int l15  = lane & 15;
    const int cg   = lane >> 4;
    const int wm   = (wave >> 2) * 128;
    const int wn   = (wave & 3) * 64;
    const int m0   = blockIdx.y * 256;
    const int n0   = blockIdx.x * 256;
    const int K = 2048, N = 2048, NT = 32;

    f32x4 acc[8][4] = {};

    auto STAGE = [&](const bf16_t* __restrict__ G, int row0, int k0, bf16_t* dst) {
#pragma unroll
        for (int i = 0; i < 2; ++i) {
            const int ch  = wave * 128 + i * 64 + lane;   // linear 16B-chunk in the unit
            const int row = ch >> 2;
            const int cs  = (ch & 3) ^ (row & 3);         // inverse-swizzled source chunk
            gload_lds16(G + (size_t)(row0 + row) * K + k0 + cs * 8,
                        dst + wave * 1024 + i * 512 + lane * 8);
        }
    };
    auto FRAG = [&](const bf16_t* u, int row) -> bf16x8 {
        return *(const bf16x8*)&u[row * 32 + ((cg ^ (row & 3)) << 3)];
    };
    auto LOADA = [&](const bf16_t* uA, int g, bf16x8* af) {
#pragma unroll
        for (int j = 0; j < 4; ++j) af[j] = FRAG(uA, wm + (g * 4 + j) * 16 + l15);
    };
    auto LOADB = [&](const bf16_t* uB, bf16x8* bfr) {
#pragma unroll
        for (int j = 0; j < 4; ++j) bfr[j] = FRAG(uB, wn + j * 16 + l15);
    };
    auto DOMFMA = [&](int g, bf16x8* af, bf16x8* bfr) {
        __builtin_amdgcn_s_setprio(1);
#pragma unroll
        for (int j = 0; j < 4; ++j)
#pragma unroll
            for (int fn = 0; fn < 4; ++fn)
                acc[g * 4 + j][fn] =
                    __builtin_amdgcn_mfma_f32_16x16x32_bf16(af[j], bfr[fn], acc[g * 4 + j][fn], 0, 0, 0);
        __builtin_amdgcn_s_setprio(0);
    };

    // prologue: stage tile0's 4 units (A0,B0,A1,B1); verify first pair, keep 4 in flight
    STAGE(A, m0, 0,  lsA[0]);
    STAGE(B, n0, 0,  lsB[0]);
    STAGE(A, m0, 32, lsA[1]);
    STAGE(B, n0, 32, lsB[1]);
    asm volatile("s_waitcnt vmcnt(4)" ::: "memory");
    __builtin_amdgcn_sched_barrier(0);
    __builtin_amdgcn_s_barrier();

    for (int t = 0; t < NT; ++t) {
        const int s0 = (2 * t) & 3, s1 = (2 * t + 1) & 3;
        const int s2 = (2 * t + 2) & 3, s3 = (2 * t + 3) & 3;
        const bool st = (t < NT - 1);
        const int kn = (t + 1) * 64;
        bf16x8 af[4], bfr[4];

        // P0 (k-half 0, fm-group 0): reads unit s0 (verified at prev P3), stages A(next,h0)
        LOADB(lsB[s0], bfr);
        LOADA(lsA[s0], 0, af);
        if (st) STAGE(A, m0, kn, lsA[s2]);
        __builtin_amdgcn_sched_barrier(0);
        __builtin_amdgcn_s_barrier();
        __builtin_amdgcn_sched_barrier(0);
        DOMFMA(0, af, bfr);
        __builtin_amdgcn_sched_barrier(0);
        __builtin_amdgcn_s_barrier();

        // P1 (h0,g1): stages B(next,h0); verify unit s1 with 4 loads still in flight
        LOADA(lsA[s0], 1, af);
        if (st) { STAGE(B, n0, kn, lsB[s2]);
                  asm volatile("s_waitcnt vmcnt(4)" ::: "memory"); }
        else      asm volatile("s_waitcnt vmcnt(0)" ::: "memory");
        __builtin_amdgcn_sched_barrier(0);
        __builtin_amdgcn_s_barrier();
        __builtin_amdgcn_sched_barrier(0);
        DOMFMA(1, af, bfr);
        __builtin_amdgcn_sched_barrier(0);
        __builtin_amdgcn_s_barrier();

        // P2 (h1,g0): reads unit s1 (verified at P1), stages A(next,h1)
        LOADB(lsB[s1], bfr);
        LOADA(lsA[s1], 0, af);
        if (st) STAGE(A, m0, kn + 32, lsA[s3]);
        __builtin_amdgcn_sched_barrier(0);
        __builtin_amdgcn_s_barrier();
        __builtin_amdgcn_sched_barrier(0);
        DOMFMA(0, af, bfr);
        __builtin_amdgcn_sched_barrier(0);
        __builtin_amdgcn_s_barrier();

        // P3 (h1,g1): stages B(next,h1); verify next tile's first unit pair, 4 in flight
        LOADA(lsA[s1], 1, af);
        if (st) { STAGE(B, n0, kn + 32, lsB[s3]);
                  asm volatile("s_waitcnt vmcnt(4)" ::: "memory"); }
        __builtin_amdgcn_sched_barrier(0);
        __builtin_amdgcn_s_barrier();
        __builtin_amdgcn_sched_barrier(0);
        DOMFMA(1, af, bfr);
        __builtin_amdgcn_sched_barrier(0);
        __builtin_amdgcn_s_barrier();
    }

    // ---- epilogue: bias + bf16 C write (C/D layout: col=lane&15, row=(lane>>4)*4+reg)
#pragma unroll
    for (int fm = 0; fm < 8; ++fm) {
        const int rb = m0 + wm + fm * 16 + ((lane >> 4) << 2);
#pragma unroll
        for (int fn = 0; fn < 4; ++fn) {
            const int colg = n0 + wn + fn * 16 + l15;
            const float bv = bias[colg];
#pragma unroll
            for (int r = 0; r < 4; ++r)
                C[(size_t)(rb + r) * N + colg] = (bf16_t)(acc[fm][fn][r] + bv);
        }
    }
    // ---- BN col sum/sumsq partials over this block's 256 rows (unique-writer, atomic-free)
#pragma unroll
    for (int fn = 0; fn < 4; ++fn) {
        const int cl = fn * 16 + l15;
        const float bv = bias[n0 + wn + cl];
        float s = 0.f, q = 0.f;
#pragma unroll
        for (int fm = 0; fm < 8; ++fm)
#pragma unroll
            for (int r = 0; r < 4; ++r) {
                const float v = acc[fm][fn][r] + bv;
                s += v; q += v * v;
            }
        s += __shfl_xor(s, 16); q += __shfl_xor(q, 16);
        s += __shfl_xor(s, 32); q += __shfl_xor(q, 32);
        if (lane < 16) { cs2[wave][cl] = s; cq2[wave][cl] = q; }
    }
    __syncthreads();
    if (tid < 256) {
        const int qn = tid >> 6, cl = tid & 63;    // col qn*64+cl covered by waves qn and qn+4
        ps [(size_t)blockIdx.y * 2048 + n0 + tid] = cs2[qn][cl] + cs2[qn + 4][cl];
        ps2[(size_t)blockIdx.y * 2048 + n0 + tid] = cq2[qn][cl] + cq2[qn + 4][cl];
    }
}

// ---------------------------------------------------------------- NT GEMM, R1/m97 structure (GEMM2/GEMM3)
__global__ __launch_bounds__(256) void gemm_bt(
    const bf16_t* __restrict__ A, const bf16_t* __restrict__ B,
    const float* __restrict__ bias, void* __restrict__ Cv,
    int N, int K, int rows_per_batch, long long b_batch_stride,
    int mode, int c_bf16,
    float* __restrict__ rsq, const float* __restrict__ rnv,
    unsigned long long* __restrict__ pkey, float* __restrict__ lseP)
{
    __shared__ bf16_t lsA[128 * 64];
    __shared__ bf16_t lsB[128 * 64];
    __shared__ float  rq2[4][64];                 // mode3: per-wave row sumsqs (unique writer)
    __shared__ float  ls2[4][64];                 // mode2: per-wave row exp-sums (unique writer)
    __shared__ unsigned long long kv2[4][64];     // mode2: per-wave row argmax keys (unique writer)
    const int tid  = threadIdx.x;
    const int lane = tid & 63;
    const int wave = tid >> 6;
    const int wm   = (wave >> 1) * 64;
    const int wn   = (wave & 1) * 64;
    const int m0   = blockIdx.y * 128;
    const int n0   = blockIdx.x * 128;
    const bf16_t* Bb = B + (long long)(m0 / rows_per_batch) * b_batch_stride;

    f32x4 acc[4][4] = {};

    const int srow = tid >> 3;
    const int scol = (tid & 7) * 8;
    for (int kt = 0; kt < K; kt += 64) {
#pragma unroll
        for (int i = 0; i < 4; ++i) {
            const int r = i * 32 + srow;
            gload_lds16(A  + (size_t)(m0 + r) * K + kt + scol, lsA + r * 64 + scol);
            gload_lds16(Bb + (size_t)(n0 + r) * K + kt + scol, lsB + r * 64 + scol);
        }
        __syncthreads();
#pragma unroll
        for (int ks = 0; ks < 2; ++ks) {
            const int kk = ks * 32 + (lane >> 4) * 8;
            bf16x8 af[4], bfr[4];
#pragma unroll
            for (int f = 0; f < 4; ++f) {
                af[f]  = *(const bf16x8*)&lsA[(wm + f * 16 + (lane & 15)) * 64 + kk];
                bfr[f] = *(const bf16x8*)&lsB[(wn + f * 16 + (lane & 15)) * 64 + kk];
            }
#pragma unroll
            for (int fm = 0; fm < 4; ++fm)
#pragma unroll
                for (int fn = 0; fn < 4; ++fn)
                    acc[fm][fn] = __builtin_amdgcn_mfma_f32_16x16x32_bf16(af[fm], bfr[fn], acc[fm][fn], 0, 0, 0);
        }
        __syncthreads();
    }

    if (mode == 2) {
        const int rnb = (m0 >> 11) * 2048;
#pragma unroll
        for (int fm = 0; fm < 4; ++fm) {
            const int mb = m0 + wm + fm * 16 + ((lane >> 4) << 2);
            const f32x4 rm = *(const f32x4*)&rnv[mb];
#pragma unroll
            for (int fn = 0; fn < 4; ++fn) {
                const float rc = rnv[rnb + n0 + wn + fn * 16 + (lane & 15)];
#pragma unroll
                for (int r = 0; r < 4; ++r)
                    acc[fm][fn][r] *= rm[r] * rc;
            }
        }
    }

#pragma unroll
    for (int fm = 0; fm < 4; ++fm) {
        const int rb = m0 + wm + fm * 16 + ((lane >> 4) << 2);
#pragma unroll
        for (int fn = 0; fn < 4; ++fn) {
            const int colg = n0 + wn + fn * 16 + (lane & 15);
            const float bv = bias ? bias[colg] : 0.0f;
            if (c_bf16) {
                bf16_t* Cb = (bf16_t*)Cv;
#pragma unroll
                for (int r = 0; r < 4; ++r)
                    Cb[(size_t)(rb + r) * N + colg] = (bf16_t)(acc[fm][fn][r] + bv);
            } else {
                float* Cf = (float*)Cv;
#pragma unroll
                for (int r = 0; r < 4; ++r)
                    Cf[(size_t)(rb + r) * N + colg] = acc[fm][fn][r] + bv;
            }
        }
    }

    if (mode == 3) {
#pragma unroll
        for (int fm = 0; fm < 4; ++fm)
#pragma unroll
            for (int r = 0; r < 4; ++r) {
                float q = 0.f;
#pragma unroll
                for (int fn = 0; fn < 4; ++fn) {
                    const float v = acc[fm][fn][r] + bias[n0 + wn + fn * 16 + (lane & 15)];
                    q += v * v;
                }
                q += __shfl_xor(q, 1); q += __shfl_xor(q, 2);
                q += __shfl_xor(q, 4); q += __shfl_xor(q, 8);
                if ((lane & 15) == 0)
                    rq2[wave][fm * 16 + ((lane >> 4) << 2) + r] = q;
            }
        __syncthreads();
        if (tid < 128) {
            const int wlo = (tid < 64) ? 0 : 2;
            const int rl  = tid & 63;
            rsq[(size_t)blockIdx.x * 4096 + m0 + tid] = rq2[wlo][rl] + rq2[wlo + 1][rl];
        }
    } else if (mode == 2) {
#pragma unroll
        for (int fm = 0; fm < 4; ++fm)
#pragma unroll
            for (int r = 0; r < 4; ++r) {
                const int rl   = fm * 16 + ((lane >> 4) << 2) + r;
                const int self = (m0 + wm + rl) & 2047;
                float best = -1.0e38f; int bi = 0x7fffffff; float se = 0.f;
#pragma unroll
                for (int fn = 0; fn < 4; ++fn) {
                    const int cg = n0 + wn + fn * 16 + (lane & 15);
                    const float v = acc[fm][fn][r];
                    if (cg != self) {
                        se += expf(10.0f * v);
                        if (v > best) { best = v; bi = cg; }
                    }
                }
#pragma unroll
                for (int st = 1; st <= 8; st <<= 1) {
                    const float ov = __shfl_xor(best, st);
                    const int   oi = __shfl_xor(bi, st);
                    if (ov > best || (ov == best && oi < bi)) { best = ov; bi = oi; }
                    se += __shfl_xor(se, st);
                }
                if ((lane & 15) == 0) {
                    unsigned u = __float_as_uint(best);
                    u = (u & 0x80000000u) ? ~u : (u | 0x80000000u);
                    kv2[wave][rl] = ((unsigned long long)u << 32) | (unsigned)(~bi);
                    ls2[wave][rl] = se;
                }
            }
        __syncthreads();
        if (tid < 128) {
            const int wlo = (tid < 64) ? 0 : 2;
            const int rl  = tid & 63;
            const unsigned long long a = kv2[wlo][rl], b = kv2[wlo + 1][rl];
            pkey[(size_t)blockIdx.x * 4096 + m0 + tid] = a > b ? a : b;
            lseP[(size_t)blockIdx.x * 4096 + m0 + tid] = ls2[wlo][rl] + ls2[wlo + 1][rl];
        }
    }
}

// ---------------------------------------------------------------- BN finalize from 8 per-mblock partials (256-row blocks)
__global__ __launch_bounds__(256) void bn_final2(const float* __restrict__ ps, const float* __restrict__ ps2,
                                                 float* __restrict__ mu, float* __restrict__ rinv)
{
    const int c = blockIdx.x * 256 + threadIdx.x;  // 0..4095
    const int b = c >> 11, col = c & 2047;
    float s = 0.f, s2 = 0.f;
    for (int i = 0; i < 8; ++i) {
        s  += ps [(size_t)(b * 8 + i) * 2048 + col];
        s2 += ps2[(size_t)(b * 8 + i) * 2048 + col];
    }
    const float m = s * (1.0f / 2048.0f);
    const float v = s2 * (1.0f / 2048.0f) - m * m;   // biased var
    mu[c]   = m;
    rinv[c] = rsqrtf(v + 1e-5f);
}

// ---------------------------------------------------------------- BN apply + ReLU on bf16 h -> bf16 hn
__global__ __launch_bounds__(256) void bn_apply(const bf16_t* __restrict__ h, const float* __restrict__ mu,
                                                const float* __restrict__ rinv, const float* __restrict__ gamma,
                                                const float* __restrict__ beta, bf16_t* __restrict__ out)
{
    const size_t base = ((size_t)blockIdx.x * 256 + threadIdx.x) * 8;
    const int col = (int)(base & 2047);
    const int br  = (int)(base >> 22);
    bf16x8 v = *(const bf16x8*)(h + base);
    bf16x8 o;
#pragma unroll
    for (int j = 0; j < 8; ++j) {
        const int c = col + j;
        const float f = (float)v[j];
        const float t = (f - mu[br * 2048 + c]) * rinv[br * 2048 + c] * gamma[c] + beta[c];
        o[j] = (bf16_t)fmaxf(t, 0.0f);
    }
    *(bf16x8*)(out + base) = o;
}

// ---------------------------------------------------------------- rn[r] = 1/max(||o_r||, 1e-12) from 16 partials
__global__ __launch_bounds__(256) void norm_final(const float* __restrict__ rsq, float* __restrict__ rn)
{
    const int r = blockIdx.x * 256 + threadIdx.x;
    float s = 0.f;
    for (int nb = 0; nb < 16; ++nb) s += rsq[(size_t)nb * 4096 + r];
    rn[r] = 1.0f / fmaxf(sqrtf(s), 1e-12f);
}

// ---------------------------------------------------------------- CC (argmax-combine folded), early-exit, 1 block/branch
__global__ __launch_bounds__(1024) void cc_labels(const unsigned long long* __restrict__ pkey,
                                                  int* __restrict__ labg)
{
    __shared__ int A_[2048];
    __shared__ int Bn[2048];
    __shared__ int Y_[2048];
    __shared__ int chg;
    const int br = blockIdx.x;
    const int t = threadIdx.x;
    if (t == 0) chg = 0;
    for (int i = t; i < 2048; i += 1024) {
        const int row = br * 2048 + i;
        unsigned long long k = 0ull;
        for (int nb = 0; nb < 16; ++nb) {
            const unsigned long long v = pkey[(size_t)nb * 4096 + row];
            k = (v > k) ? v : k;
        }
        Y_[i] = (int)~((unsigned)(k & 0xFFFFFFFFull));
        A_[i] = i;
    }
    __syncthreads();
    for (int it = 0; it < 32; ++it) {
        for (int i = t; i < 2048; i += 1024) Bn[i] = min(A_[i], A_[Y_[i]]);
        __syncthreads();
        for (int i = t; i < 2048; i += 1024) atomicMin(&Bn[Y_[i]], A_[i]);
        __syncthreads();
        int ch = 0;
        for (int i = t; i < 2048; i += 1024) {
            const int b = Bn[i];
            const int nv = min(b, Bn[b]);
            if (nv != A_[i]) { ch = 1; A_[i] = nv; }
        }
        if (ch) atomicOr(&chg, 1);
        __syncthreads();
        const int c = chg;
        __syncthreads();
        if (t == 0) chg = 0;
        if (!c) break;
    }
    for (int i = t; i < 2048; i += 1024) labg[br * 2048 + i] = A_[i];
}

// ---------------------------------------------------------------- per-row term from bf16 sim + exact LSE partials
__global__ __launch_bounds__(256) void loss_rows(const bf16_t* __restrict__ simb, const int* __restrict__ labels,
                                                 const float* __restrict__ lseP, float* __restrict__ terms)
{
    const int row = blockIdx.x;
    const int br  = row >> 11;
    const int* lab = labels + ((1 - br) << 11);
    const int self = row & 2047;
    const int li = lab[self];
    const int t = threadIdx.x;
    const bf16x8 v8 = *(const bf16x8*)(simb + (size_t)row * 2048 + t * 8);
    float psum = 0.f; int pc = 0;
#pragma unroll
    for (int j = 0; j < 8; ++j) {
        const int c = t * 8 + j;
        if (c == self) continue;
        if (lab[c] == li) { psum += 10.0f * (float)v8[j]; pc++; }
    }
    __shared__ float PS[256]; __shared__ int PC[256];
    PS[t] = psum; PC[t] = pc;
    __syncthreads();
    for (int off = 128; off; off >>= 1) {
        if (t < off) { PS[t] += PS[t + off]; PC[t] += PC[t + off]; }
        __syncthreads();
    }
    if (t == 0) {
        float se = 0.f;
        for (int nb = 0; nb < 16; ++nb) se += lseP[(size_t)nb * 4096 + row];
        terms[row] = logf(se) - PS[0] / (float)PC[0];
    }
}

// ---------------------------------------------------------------- final deterministic reduce
__global__ __launch_bounds__(1024) void final_reduce(const float* __restrict__ terms, float* __restrict__ out)
{
    const int t = threadIdx.x;
    float s = terms[t] + terms[t + 1024] + terms[t + 2048] + terms[t + 3072];
    __shared__ float S[1024];
    S[t] = s;
    __syncthreads();
    for (int off = 512; off; off >>= 1) { if (t < off) S[t] += S[t + off]; __syncthreads(); }
    if (t == 0) out[0] = S[0] * (1.0f / 4096.0f);
}

// ---------------------------------------------------------------- launch
extern "C" void kernel_launch(void* const* d_in, const int* in_sizes, int n_in,
                              void* d_out, int out_size, void* d_ws, size_t ws_size,
                              hipStream_t stream)
{
    const float* x1    = (const float*)d_in[0];
    const float* x2    = (const float*)d_in[1];
    const float* W1    = (const float*)d_in[2];
    const float* b1    = (const float*)d_in[3];
    const float* gamma = (const float*)d_in[4];
    const float* beta  = (const float*)d_in[5];
    const float* W2    = (const float*)d_in[6];
    const float* b2    = (const float*)d_in[7];

    char* ws = (char*)d_ws;
    const size_t MB = 1024ull * 1024ull;
    const size_t NN = 2048ull * 2048ull;
    bf16_t* W1b    = (bf16_t*)(ws + 0);
    bf16_t* W2b    = (bf16_t*)(ws + 8 * MB);
    bf16_t* xcatb  = (bf16_t*)(ws + 16 * MB);
    bf16_t* hnb    = (bf16_t*)(ws + 16 * MB);
    bf16_t* hb16   = (bf16_t*)(ws + 32 * MB);
    bf16_t* ob16   = (bf16_t*)(ws + 64 * MB);
    bf16_t* simb   = (bf16_t*)(ws + 0);
    float*  psA    = (float*)(ws + 80 * MB);               // [16][2048] col sums
    float*  psB    = psA + 32 * 2048;                       // [16][2048] col sumsq
    float*  rsq    = psB + 32 * 2048;                       // [16][4096] row sumsq
    float*  mu     = rsq + 16 * 4096;                       // [2][2048]
    float*  rinv   = mu + 4096;
    float*  rn     = rinv + 4096;                           // [4096]
    float*  lseP   = rn + 4096;                             // [16][4096]
    unsigned long long* pkey = (unsigned long long*)(lseP + 16 * 4096);  // [16][4096]
    int*    labels = (int*)(pkey + 16 * 4096);
    float*  terms  = (float*)(labels + 4096);

    // fused casts
    cast_all<<<16384, 256, 0, stream>>>(x1, x2, W1, W2, xcatb, W1b, W2b);

    // h = xcat @ W1^T + b1 -> bf16, fused BN-stat partials  [8-phase 256^2 kernel, A/B vs gemm_bt below]
    gemm8<<<dim3(8, 16), 512, 0, stream>>>(xcatb, W1b, b1, hb16, psA, psB);
    bn_final2<<<16, 256, 0, stream>>>(psA, psB, mu, rinv);
    bn_apply<<<4096, 256, 0, stream>>>(hb16, mu, rinv, gamma, beta, hnb);

    // o = hn @ W2^T + b2 -> bf16, fused row-sumsq partials
    gemm_bt<<<dim3(16, 32), 256, 0, stream>>>(hnb, W2b, b2, ob16, 2048, 2048, 1 << 30, 0,
                                              3, 1, rsq, nullptr, nullptr, nullptr);
    norm_final<<<16, 256, 0, stream>>>(rsq, rn);

    // sim = [o1@o1^T ; o2@o2^T] * rn_m*rn_n -> bf16, fused row-argmax + row-LSE partials
    gemm_bt<<<dim3(16, 32), 256, 0, stream>>>(ob16, ob16, nullptr, simb, 2048, 2048, 2048, (long long)NN,
                                              2, 1, nullptr, rn, pkey, lseP);

    // CC (argmax folded, early-exit) -> loss
    cc_labels<<<2, 1024, 0, stream>>>(pkey, labels);
    loss_rows<<<4096, 256, 0, stream>>>(simb, labels, lseP, terms);
    final_reduce<<<1, 1024, 0, stream>>>(terms, (float*)d_out);
}

// Round 10
// 216.356 us; speedup vs baseline: 1.2201x; 1.2201x over previous
//
#include <hip/hip_runtime.h>
#include <hip/hip_bf16.h>

typedef __bf16 bf16_t;
typedef __bf16 bf16x4 __attribute__((ext_vector_type(4)));
typedef __bf16 bf16x8 __attribute__((ext_vector_type(8)));
typedef float  f32x4  __attribute__((ext_vector_type(4)));

// ---------------------------------------------------------------- helpers
__device__ __forceinline__ void gload_lds16(const void* g, void* l)
{
    __builtin_amdgcn_global_load_lds((__attribute__((address_space(1))) void*)g,
                                     (__attribute__((address_space(3))) void*)l,
                                     16, 0, 0);
}

// ---------------------------------------------------------------- fused fp32 -> bf16 casts (x1|x2 -> xcat, W1, W2)
__global__ __launch_bounds__(256) void cast_all(const float* __restrict__ x1, const float* __restrict__ x2,
                                                const float* __restrict__ W1, const float* __restrict__ W2,
                                                bf16_t* __restrict__ xcatb, bf16_t* __restrict__ W1b,
                                                bf16_t* __restrict__ W2b)
{
    const size_t i  = ((size_t)blockIdx.x * 256 + threadIdx.x) * 4;
    const size_t M4 = 1ull << 22;              // 4M elements per region
    const size_t r  = i >> 22;
    const size_t off = i & (M4 - 1);
    const float* src; bf16_t* dst;
    if (r == 0)      { src = x1; dst = xcatb; }
    else if (r == 1) { src = x2; dst = xcatb + M4; }
    else if (r == 2) { src = W1; dst = W1b; }
    else             { src = W2; dst = W2b; }
    f32x4 v = *(const f32x4*)(src + off);
    bf16x4 o;
    o[0] = (bf16_t)v[0]; o[1] = (bf16_t)v[1]; o[2] = (bf16_t)v[2]; o[3] = (bf16_t)v[3];
    *(bf16x4*)(dst + off) = o;
}

// ---------------------------------------------------------------- counted-vmcnt GEMM: 256x128 tile, BK=64, full-chip grid
// Grid (16 nblk)x(16 mblk) = 256 blocks = 1/CU. 8 waves (4m x 2n), per-wave 64x64, acc[4][4].
// Ring of 4 k32 units per matrix (A-unit 256x32=16KB, B-unit 128x32=8KB; 96KB LDS total).
// 2 phases/K-tile: {8 ds_read frags || stage 3 loads of tile t+1 -> vmcnt(3) -> barrier ->
// setprio+16 MFMA+setprio -> barrier}. vmcnt never 0 in the main loop (counted: 3 younger in flight).
// LDS chunk perm: 16B chunk c of row stored at (c + (row>>1))&3 -> 2-way-free ds_read banks;
// inverse perm applied on the global staging source (rule: both-sides-or-neither).
// mode 1: + col sum/sumsq partials (BN). mode 2: + rn scaling, row argmax + LSE partials.
// mode 3: + row sumsq partials. C always bf16. MFMA k-order identical to the m97 kernel.
__global__ __launch_bounds__(512, 1) void gemm8b(
    const bf16_t* __restrict__ A, const bf16_t* __restrict__ B,
    const float* __restrict__ bias, bf16_t* __restrict__ C,
    long long b_batch_stride, int mode,
    float* __restrict__ ps, float* __restrict__ ps2,
    float* __restrict__ rsq, const float* __restrict__ rnv,
    unsigned long long* __restrict__ pkey, float* __restrict__ lseP)
{
    __shared__ bf16_t lsA[4][256 * 32];
    __shared__ bf16_t lsB[4][128 * 32];
    __shared__ float  cs2[8][64], cq2[8][64];     // mode1
    __shared__ float  rq2[8][64];                 // mode3
    __shared__ float  ls2[8][64];                 // mode2
    __shared__ unsigned long long kv2[8][64];     // mode2
    const int tid  = threadIdx.x;
    const int lane = tid & 63;
    const int wave = tid >> 6;
    const int l15  = lane & 15;
    const int cg   = lane >> 4;
    const int wm   = (wave >> 1) * 64;            // 4 m-groups
    const int wn   = (wave & 1) * 64;             // 2 n-halves
    const int m0   = blockIdx.y * 256;
    const int n0   = blockIdx.x * 128;
    const int K = 2048, N = 2048, NT = 32;
    const bf16_t* Bb = B + (size_t)(m0 >> 11) * b_batch_stride;

    f32x4 acc[4][4] = {};

    auto STAGE_A = [&](int k0, bf16_t* dst) {
#pragma unroll
        for (int i = 0; i < 2; ++i) {
            const int ch  = wave * 128 + i * 64 + lane;        // dest 16B chunk, linear in lane
            const int row = ch >> 2;
            const int cs  = ((ch & 3) - ((row >> 1) & 3)) & 3; // inverse perm on source
            gload_lds16(A + (size_t)(m0 + row) * K + k0 + cs * 8, dst + ch * 8);
        }
    };
    auto STAGE_B = [&](int k0, bf16_t* dst) {
        const int ch  = wave * 64 + lane;
        const int row = ch >> 2;
        const int cs  = ((ch & 3) - ((row >> 1) & 3)) & 3;
        gload_lds16(Bb + (size_t)(n0 + row) * K + k0 + cs * 8, dst + ch * 8);
    };
    auto FRAG = [&](const bf16_t* u, int row) -> bf16x8 {
        const int p = (cg + (row >> 1)) & 3;                   // stored position of chunk cg
        return *(const bf16x8*)&u[row * 32 + p * 8];
    };

    // prologue: stage tile0's two unit-pairs; verify pair0, keep pair1's 3 loads in flight
    STAGE_A(0,  lsA[0]); STAGE_B(0,  lsB[0]);
    STAGE_A(32, lsA[1]); STAGE_B(32, lsB[1]);
    asm volatile("s_waitcnt vmcnt(3)" ::: "memory");
    __builtin_amdgcn_sched_barrier(0);
    __builtin_amdgcn_s_barrier();

    for (int t = 0; t < NT; ++t) {
        const int s0 = (2 * t) & 3, s1 = (2 * t + 1) & 3;
        const int s2 = (2 * t + 2) & 3, s3 = (2 * t + 3) & 3;
        const bool st = (t < NT - 1);
        const int kn = (t + 1) * 64;
        bf16x8 af[4], bfr[4];

        // ---- phase A: unit s0 (verified last phase); stage pair for next tile's h0
#pragma unroll
        for (int f = 0; f < 4; ++f) af[f]  = FRAG(lsA[s0], wm + f * 16 + l15);
#pragma unroll
        for (int f = 0; f < 4; ++f) bfr[f] = FRAG(lsB[s0], wn + f * 16 + l15);
        if (st) { STAGE_A(kn, lsA[s2]); STAGE_B(kn, lsB[s2]);
                  asm volatile("s_waitcnt vmcnt(3)" ::: "memory"); }   // confirms s1
        else      asm volatile("s_waitcnt vmcnt(0)" ::: "memory");
        __builtin_amdgcn_sched_barrier(0);
        __builtin_amdgcn_s_barrier();
        __builtin_amdgcn_sched_barrier(0);
        __builtin_amdgcn_s_setprio(1);
#pragma unroll
        for (int fm = 0; fm < 4; ++fm)
#pragma unroll
            for (int fn = 0; fn < 4; ++fn)
                acc[fm][fn] = __builtin_amdgcn_mfma_f32_16x16x32_bf16(af[fm], bfr[fn], acc[fm][fn], 0, 0, 0);
        __builtin_amdgcn_s_setprio(0);
        __builtin_amdgcn_sched_barrier(0);
        __builtin_amdgcn_s_barrier();

        // ---- phase B: unit s1; stage pair for next tile's h1
#pragma unroll
        for (int f = 0; f < 4; ++f) af[f]  = FRAG(lsA[s1], wm + f * 16 + l15);
#pragma unroll
        for (int f = 0; f < 4; ++f) bfr[f] = FRAG(lsB[s1], wn + f * 16 + l15);
        if (st) { STAGE_A(kn + 32, lsA[s3]); STAGE_B(kn + 32, lsB[s3]);
                  asm volatile("s_waitcnt vmcnt(3)" ::: "memory"); }   // confirms s2
        __builtin_amdgcn_sched_barrier(0);
        __builtin_amdgcn_s_barrier();
        __builtin_amdgcn_sched_barrier(0);
        __builtin_amdgcn_s_setprio(1);
#pragma unroll
        for (int fm = 0; fm < 4; ++fm)
#pragma unroll
            for (int fn = 0; fn < 4; ++fn)
                acc[fm][fn] = __builtin_amdgcn_mfma_f32_16x16x32_bf16(af[fm], bfr[fn], acc[fm][fn], 0, 0, 0);
        __builtin_amdgcn_s_setprio(0);
        __builtin_amdgcn_sched_barrier(0);
        __builtin_amdgcn_s_barrier();
    }

    // ---- mode2: fold row-normalization: acc[m][n] *= rn[m]*rn[n]
    if (mode == 2) {
        const int rnb = (m0 >> 11) * 2048;
#pragma unroll
        for (int fm = 0; fm < 4; ++fm) {
            const int mb = m0 + wm + fm * 16 + cg * 4;
            const f32x4 rm = *(const f32x4*)&rnv[mb];
#pragma unroll
            for (int fn = 0; fn < 4; ++fn) {
                const float rc = rnv[rnb + n0 + wn + fn * 16 + l15];
#pragma unroll
                for (int r = 0; r < 4; ++r)
                    acc[fm][fn][r] *= rm[r] * rc;
            }
        }
    }

    // ---- C write (+bias), bf16. C/D layout: col = lane&15, row = (lane>>4)*4 + reg
#pragma unroll
    for (int fm = 0; fm < 4; ++fm) {
        const int rb = m0 + wm + fm * 16 + cg * 4;
#pragma unroll
        for (int fn = 0; fn < 4; ++fn) {
            const int colg = n0 + wn + fn * 16 + l15;
            const float bv = bias ? bias[colg] : 0.0f;
#pragma unroll
            for (int r = 0; r < 4; ++r)
                C[(size_t)(rb + r) * N + colg] = (bf16_t)(acc[fm][fn][r] + bv);
        }
    }

    if (mode == 1) {
        // col sum/sumsq over this block's 256 rows. Col j: waves {p,p+2,p+4,p+6}, p=j>>6.
#pragma unroll
        for (int fn = 0; fn < 4; ++fn) {
            const int cl = fn * 16 + l15;                  // 0..63 within wave's cols
            const float bv = bias[n0 + wn + cl];
            float s = 0.f, q = 0.f;
#pragma unroll
            for (int fm = 0; fm < 4; ++fm)
#pragma unroll
                for (int r = 0; r < 4; ++r) {
                    const float v = acc[fm][fn][r] + bv;
                    s += v; q += v * v;
                }
            s += __shfl_xor(s, 16); q += __shfl_xor(q, 16);
            s += __shfl_xor(s, 32); q += __shfl_xor(q, 32);
            if (lane < 16) { cs2[wave][cl] = s; cq2[wave][cl] = q; }
        }
        __syncthreads();
        if (tid < 128) {
            const int p = tid >> 6, cl = tid & 63;
            ps [(size_t)blockIdx.y * 2048 + n0 + tid] =
                cs2[p][cl] + cs2[p + 2][cl] + cs2[p + 4][cl] + cs2[p + 6][cl];
            ps2[(size_t)blockIdx.y * 2048 + n0 + tid] =
                cq2[p][cl] + cq2[p + 2][cl] + cq2[p + 4][cl] + cq2[p + 6][cl];
        }
    } else if (mode == 3) {
        // row sumsq of (acc+bias) over this block's 128 cols. Row j: waves {2mg,2mg+1}, mg=j>>6.
#pragma unroll
        for (int fm = 0; fm < 4; ++fm)
#pragma unroll
            for (int r = 0; r < 4; ++r) {
                float q = 0.f;
#pragma unroll
                for (int fn = 0; fn < 4; ++fn) {
                    const float v = acc[fm][fn][r] + bias[n0 + wn + fn * 16 + l15];
                    q += v * v;
                }
                q += __shfl_xor(q, 1); q += __shfl_xor(q, 2);
                q += __shfl_xor(q, 4); q += __shfl_xor(q, 8);
                if (l15 == 0) rq2[wave][fm * 16 + cg * 4 + r] = q;
            }
        __syncthreads();
        if (tid < 256) {
            const int mg = tid >> 6, rl = tid & 63;
            rsq[(size_t)blockIdx.x * 4096 + m0 + tid] = rq2[2 * mg][rl] + rq2[2 * mg + 1][rl];
        }
    } else if (mode == 2) {
        // row argmax + LSE over this block's 128 cols (scaled acc), self excluded.
#pragma unroll
        for (int fm = 0; fm < 4; ++fm)
#pragma unroll
            for (int r = 0; r < 4; ++r) {
                const int rl   = fm * 16 + cg * 4 + r;
                const int self = (m0 + wm + rl) & 2047;
                float best = -1.0e38f; int bi = 0x7fffffff; float se = 0.f;
#pragma unroll
                for (int fn = 0; fn < 4; ++fn) {
                    const int cgl = n0 + wn + fn * 16 + l15;
                    const float v = acc[fm][fn][r];
                    if (cgl != self) {
                        se += expf(10.0f * v);
                        if (v > best) { best = v; bi = cgl; }
                    }
                }
#pragma unroll
                for (int st2 = 1; st2 <= 8; st2 <<= 1) {
                    const float ov = __shfl_xor(best, st2);
                    const int   oi = __shfl_xor(bi, st2);
                    if (ov > best || (ov == best && oi < bi)) { best = ov; bi = oi; }
                    se += __shfl_xor(se, st2);
                }
                if (l15 == 0) {
                    unsigned u = __float_as_uint(best);
                    u = (u & 0x80000000u) ? ~u : (u | 0x80000000u);
                    kv2[wave][rl] = ((unsigned long long)u << 32) | (unsigned)(~bi);
                    ls2[wave][rl] = se;
                }
            }
        __syncthreads();
        if (tid < 256) {
            const int mg = tid >> 6, rl = tid & 63;
            const unsigned long long a = kv2[2 * mg][rl], b = kv2[2 * mg + 1][rl];
            pkey[(size_t)blockIdx.x * 4096 + m0 + tid] = a > b ? a : b;
            lseP[(size_t)blockIdx.x * 4096 + m0 + tid] = ls2[2 * mg][rl] + ls2[2 * mg + 1][rl];
        }
    }
}

// ---------------------------------------------------------------- BN finalize from 8 per-mblock partials (256-row blocks)
__global__ __launch_bounds__(256) void bn_final2(const float* __restrict__ ps, const float* __restrict__ ps2,
                                                 float* __restrict__ mu, float* __restrict__ rinv)
{
    const int c = blockIdx.x * 256 + threadIdx.x;  // 0..4095
    const int b = c >> 11, col = c & 2047;
    float s = 0.f, s2 = 0.f;
    for (int i = 0; i < 8; ++i) {
        s  += ps [(size_t)(b * 8 + i) * 2048 + col];
        s2 += ps2[(size_t)(b * 8 + i) * 2048 + col];
    }
    const float m = s * (1.0f / 2048.0f);
    const float v = s2 * (1.0f / 2048.0f) - m * m;   // biased var
    mu[c]   = m;
    rinv[c] = rsqrtf(v + 1e-5f);
}

// ---------------------------------------------------------------- BN apply + ReLU on bf16 h -> bf16 hn
__global__ __launch_bounds__(256) void bn_apply(const bf16_t* __restrict__ h, const float* __restrict__ mu,
                                                const float* __restrict__ rinv, const float* __restrict__ gamma,
                                                const float* __restrict__ beta, bf16_t* __restrict__ out)
{
    const size_t base = ((size_t)blockIdx.x * 256 + threadIdx.x) * 8;
    const int col = (int)(base & 2047);
    const int br  = (int)(base >> 22);
    bf16x8 v = *(const bf16x8*)(h + base);
    bf16x8 o;
#pragma unroll
    for (int j = 0; j < 8; ++j) {
        const int c = col + j;
        const float f = (float)v[j];
        const float t = (f - mu[br * 2048 + c]) * rinv[br * 2048 + c] * gamma[c] + beta[c];
        o[j] = (bf16_t)fmaxf(t, 0.0f);
    }
    *(bf16x8*)(out + base) = o;
}

// ---------------------------------------------------------------- rn[r] = 1/max(||o_r||, 1e-12) from 16 partials
__global__ __launch_bounds__(256) void norm_final(const float* __restrict__ rsq, float* __restrict__ rn)
{
    const int r = blockIdx.x * 256 + threadIdx.x;
    float s = 0.f;
    for (int nb = 0; nb < 16; ++nb) s += rsq[(size_t)nb * 4096 + r];
    rn[r] = 1.0f / fmaxf(sqrtf(s), 1e-12f);
}

// ---------------------------------------------------------------- CC (argmax-combine folded), early-exit, 1 block/branch
__global__ __launch_bounds__(1024) void cc_labels(const unsigned long long* __restrict__ pkey,
                                                  int* __restrict__ labg)
{
    __shared__ int A_[2048];
    __shared__ int Bn[2048];
    __shared__ int Y_[2048];
    __shared__ int chg;
    const int br = blockIdx.x;
    const int t = threadIdx.x;
    if (t == 0) chg = 0;
    for (int i = t; i < 2048; i += 1024) {
        const int row = br * 2048 + i;
        unsigned long long k = 0ull;
        for (int nb = 0; nb < 16; ++nb) {
            const unsigned long long v = pkey[(size_t)nb * 4096 + row];
            k = (v > k) ? v : k;
        }
        Y_[i] = (int)~((unsigned)(k & 0xFFFFFFFFull));
        A_[i] = i;
    }
    __syncthreads();
    for (int it = 0; it < 32; ++it) {
        for (int i = t; i < 2048; i += 1024) Bn[i] = min(A_[i], A_[Y_[i]]);
        __syncthreads();
        for (int i = t; i < 2048; i += 1024) atomicMin(&Bn[Y_[i]], A_[i]);
        __syncthreads();
        int ch = 0;
        for (int i = t; i < 2048; i += 1024) {
            const int b = Bn[i];
            const int nv = min(b, Bn[b]);
            if (nv != A_[i]) { ch = 1; A_[i] = nv; }
        }
        if (ch) atomicOr(&chg, 1);
        __syncthreads();
        const int c = chg;
        __syncthreads();
        if (t == 0) chg = 0;
        if (!c) break;
    }
    for (int i = t; i < 2048; i += 1024) labg[br * 2048 + i] = A_[i];
}

// ---------------------------------------------------------------- per-row term from bf16 sim + exact LSE partials
__global__ __launch_bounds__(256) void loss_rows(const bf16_t* __restrict__ simb, const int* __restrict__ labels,
                                                 const float* __restrict__ lseP, float* __restrict__ terms)
{
    const int row = blockIdx.x;
    const int br  = row >> 11;
    const int* lab = labels + ((1 - br) << 11);
    const int self = row & 2047;
    const int li = lab[self];
    const int t = threadIdx.x;
    const bf16x8 v8 = *(const bf16x8*)(simb + (size_t)row * 2048 + t * 8);
    float psum = 0.f; int pc = 0;
#pragma unroll
    for (int j = 0; j < 8; ++j) {
        const int c = t * 8 + j;
        if (c == self) continue;
        if (lab[c] == li) { psum += 10.0f * (float)v8[j]; pc++; }
    }
    __shared__ float PS[256]; __shared__ int PC[256];
    PS[t] = psum; PC[t] = pc;
    __syncthreads();
    for (int off = 128; off; off >>= 1) {
        if (t < off) { PS[t] += PS[t + off]; PC[t] += PC[t + off]; }
        __syncthreads();
    }
    if (t == 0) {
        float se = 0.f;
        for (int nb = 0; nb < 16; ++nb) se += lseP[(size_t)nb * 4096 + row];
        terms[row] = logf(se) - PS[0] / (float)PC[0];
    }
}

// ---------------------------------------------------------------- final deterministic reduce
__global__ __launch_bounds__(1024) void final_reduce(const float* __restrict__ terms, float* __restrict__ out)
{
    const int t = threadIdx.x;
    float s = terms[t] + terms[t + 1024] + terms[t + 2048] + terms[t + 3072];
    __shared__ float S[1024];
    S[t] = s;
    __syncthreads();
    for (int off = 512; off; off >>= 1) { if (t < off) S[t] += S[t + off]; __syncthreads(); }
    if (t == 0) out[0] = S[0] * (1.0f / 4096.0f);
}

// ---------------------------------------------------------------- launch
extern "C" void kernel_launch(void* const* d_in, const int* in_sizes, int n_in,
                              void* d_out, int out_size, void* d_ws, size_t ws_size,
                              hipStream_t stream)
{
    const float* x1    = (const float*)d_in[0];
    const float* x2    = (const float*)d_in[1];
    const float* W1    = (const float*)d_in[2];
    const float* b1    = (const float*)d_in[3];
    const float* gamma = (const float*)d_in[4];
    const float* beta  = (const float*)d_in[5];
    const float* W2    = (const float*)d_in[6];
    const float* b2    = (const float*)d_in[7];

    char* ws = (char*)d_ws;
    const size_t MB = 1024ull * 1024ull;
    const size_t NN = 2048ull * 2048ull;
    bf16_t* W1b    = (bf16_t*)(ws + 0);
    bf16_t* W2b    = (bf16_t*)(ws + 8 * MB);
    bf16_t* xcatb  = (bf16_t*)(ws + 16 * MB);
    bf16_t* hnb    = (bf16_t*)(ws + 16 * MB);
    bf16_t* hb16   = (bf16_t*)(ws + 32 * MB);
    bf16_t* ob16   = (bf16_t*)(ws + 64 * MB);
    bf16_t* simb   = (bf16_t*)(ws + 0);
    float*  psA    = (float*)(ws + 80 * MB);               // [16][2048] col sums
    float*  psB    = psA + 32 * 2048;                       // [16][2048] col sumsq
    float*  rsq    = psB + 32 * 2048;                       // [16][4096] row sumsq
    float*  mu     = rsq + 16 * 4096;                       // [2][2048]
    float*  rinv   = mu + 4096;
    float*  rn     = rinv + 4096;                           // [4096]
    float*  lseP   = rn + 4096;                             // [16][4096]
    unsigned long long* pkey = (unsigned long long*)(lseP + 16 * 4096);  // [16][4096]
    int*    labels = (int*)(pkey + 16 * 4096);
    float*  terms  = (float*)(labels + 4096);

    // fused casts
    cast_all<<<16384, 256, 0, stream>>>(x1, x2, W1, W2, xcatb, W1b, W2b);

    // h = xcat @ W1^T + b1 -> bf16, fused BN-stat partials
    gemm8b<<<dim3(16, 16), 512, 0, stream>>>(xcatb, W1b, b1, hb16, 0, 1,
                                             psA, psB, nullptr, nullptr, nullptr, nullptr);
    bn_final2<<<16, 256, 0, stream>>>(psA, psB, mu, rinv);
    bn_apply<<<4096, 256, 0, stream>>>(hb16, mu, rinv, gamma, beta, hnb);

    // o = hn @ W2^T + b2 -> bf16, fused row-sumsq partials
    gemm8b<<<dim3(16, 16), 512, 0, stream>>>(hnb, W2b, b2, ob16, 0, 3,
                                             nullptr, nullptr, rsq, nullptr, nullptr, nullptr);
    norm_final<<<16, 256, 0, stream>>>(rsq, rn);

    // sim = [o1@o1^T ; o2@o2^T] * rn_m*rn_n -> bf16, fused row-argmax + row-LSE partials
    gemm8b<<<dim3(16, 16), 512, 0, stream>>>(ob16, ob16, nullptr, simb, (long long)NN, 2,
                                             nullptr, nullptr, nullptr, rn, pkey, lseP);

    // CC (argmax folded, early-exit) -> loss
    cc_labels<<<2, 1024, 0, stream>>>(pkey, labels);
    loss_rows<<<4096, 256, 0, stream>>>(simb, labels, lseP, terms);
    final_reduce<<<1, 1024, 0, stream>>>(terms, (float*)d_out);
}